// Round 2
// 163.669 us; speedup vs baseline: 1.0242x; 1.0242x over previous
//
#include <hip/hip_runtime.h>
#include <hip/hip_fp16.h>

// Problem constants (from reference):
//   x:    (B=2, C=8, F=80, N=128, N=128) fp32
//   quad: (H=512, W=1024) int32 in [0, F)
//   uv:   (H, W, 2) fp32 in [0, N-1)
//   out:  (B, C, H, W) fp32
#define BC   16                 // B*C
#define FD   80
#define ND   128
#define NN   (ND * ND)          // 16384
#define HW   (512 * 1024)       // 524288 = 2^19
#define HW_SHIFT 19

#define YH_BYTES ((size_t)FD * NN * BC * sizeof(__half))   // 41,943,040

// Native clang vector types — required for __builtin_nontemporal_load
// (HIP_vector_type structs are rejected by the builtin).
typedef float  vf4 __attribute__((ext_vector_type(4)));
typedef float  vf2 __attribute__((ext_vector_type(2)));

// ---------------------------------------------------------------------------
// Kernel 1: repack x[bc][f][v][u] (fp32) -> y[f][v][u][bc] (fp16, channels
// innermost). One block per (f, v) row: 128 u x 16 ch = 2048 values.
// v3: nontemporal vf4 loads (x is read exactly once -- keep L2/L3 free
// for y), float4 LDS layout so phase-1 is 1x ds_write_b128 per load (b128
// 4-way is the structural floor) and phase-2 scalar reads are
// bank-conflict-free: word = ((u>>2)*17 + c)*4 + (u&3);
// bank = 4*(u>>2) + (u&3) + 4k covers all 32 banks bijectively over u=0..31.
// ---------------------------------------------------------------------------
__global__ __launch_bounds__(256)
void repack_kernel(const float* __restrict__ x, __half* __restrict__ y)
{
    const int fv  = blockIdx.x;          // 0 .. FD*ND-1
    const int f   = fv >> 7;             // fv / ND
    const int v   = fv & (ND - 1);
    const int tid = threadIdx.x;

    __shared__ vf4 lds4[32 * 17];        // [u4][c], stride 17 float4s (8704 B)

    // Phase 1: 512 float4 loads cover 16 ch x 128 u; coalesced along u.
#pragma unroll
    for (int r = 0; r < 2; ++r) {
        const int i4 = tid + r * 256;    // 0..511
        const int c  = i4 >> 5;          // 0..15
        const int u4 = i4 & 31;          // 0..31 (float4 index along u)
        const vf4 val = __builtin_nontemporal_load(
            (const vf4*)(x + (((size_t)c * FD + f) * ND + v) * ND + u4 * 4));
        lds4[u4 * 17 + c] = val;         // single ds_write_b128
    }
    __syncthreads();

    // Phase 2: each thread packs 8 consecutive halves (16 B).
    const int u  = tid >> 1;
    const int c0 = (tid & 1) * 8;
    const float* lf = (const float*)lds4;
    // float for (u, c) lives at word ((u>>2)*17 + c)*4 + (u&3)
    const int w0 = ((u >> 2) * 17 + c0) * 4 + (u & 3);
    uint4 rr;
    unsigned* rp = (unsigned*)&rr;
#pragma unroll
    for (int j = 0; j < 4; ++j) {
        const __half2 h = __floats2half2_rn(lf[w0 + (2 * j) * 4],
                                            lf[w0 + (2 * j + 1) * 4]);
        rp[j] = *(const unsigned*)&h;
    }
    uint4* y4 = (uint4*)(y + (size_t)fv * ND * BC);
    y4[tid] = rr;                        // 4 KB contiguous per block
}

// ---------------------------------------------------------------------------
// Kernel 2: gather. ONE thread per pixel, all 16 channels.
// Per pixel: 2 NT metadata loads, 8 uint4 texel loads (the 64B v-row span
// (u0,u0+1)x16ch is fully consumed), 16 coalesced NT scalar stores.
// v3: float2-packed accumulators (v_pk_fma_f32), NT metadata loads.
// ---------------------------------------------------------------------------
__device__ inline void acc8p(float2* o2, uint4 t, float w)
{
    const unsigned* p = (const unsigned*)&t;
#pragma unroll
    for (int j = 0; j < 4; ++j) {
        const float2 fp = __half22float2(*(const __half2*)&p[j]);
        o2[j].x += fp.x * w;
        o2[j].y += fp.y * w;
    }
}

__global__ __launch_bounds__(256)
void gather_kernel(const __half* __restrict__ y,
                   const int*    __restrict__ quad,
                   const float2* __restrict__ uv2,
                   float* __restrict__ out)
{
    const int pix = blockIdx.x * 256 + threadIdx.x;

    const vf2 tv = __builtin_nontemporal_load((const vf2*)&uv2[pix]);
    const int f  = __builtin_nontemporal_load(&quad[pix]);

    const float u = tv.x;
    const float v = tv.y;

    int u0 = (int)floorf(u);
    int v0 = (int)floorf(v);
    u0 = min(max(u0, 0), ND - 2);
    v0 = min(max(v0, 0), ND - 2);

    // Issue all 8 texel loads (128 B, all consumed) before the weight math.
    const size_t base = (((size_t)f * ND + v0) * ND + u0) * BC;
    const uint4* r0 = (const uint4*)(y + base);                    // (v0,  u0..u0+1)
    const uint4* r1 = (const uint4*)(y + base + (size_t)ND * BC);  // (v0+1,u0..u0+1)
    const uint4 a0 = r0[0], a1 = r0[1];   // (v0,u0)   ch0-7, ch8-15
    const uint4 b0 = r0[2], b1 = r0[3];   // (v0,u0+1)
    const uint4 c0 = r1[0], c1 = r1[1];   // (v1,u0)
    const uint4 d0 = r1[2], d1 = r1[3];   // (v1,u0+1)

    const float du = u - (float)u0;
    const float dv = v - (float)v0;
    const float w00 = (1.0f - du) * (1.0f - dv);
    const float w01 = du * (1.0f - dv);
    const float w10 = (1.0f - du) * dv;
    const float w11 = du * dv;

    float2 o2[8];                        // ch pairs: o2[0..3]=ch0-7, o2[4..7]=ch8-15
#pragma unroll
    for (int j = 0; j < 8; ++j) o2[j] = make_float2(0.0f, 0.0f);

    acc8p(o2,     a0, w00); acc8p(o2 + 4, a1, w00);
    acc8p(o2,     b0, w01); acc8p(o2 + 4, b1, w01);
    acc8p(o2,     c0, w10); acc8p(o2 + 4, c1, w10);
    acc8p(o2,     d0, w11); acc8p(o2 + 4, d1, w11);

    // 16 coalesced scalar stores (64 consecutive pixels per wave per plane).
    const float* o = (const float*)o2;
#pragma unroll
    for (int c = 0; c < BC; ++c)
        __builtin_nontemporal_store(o[c], &out[(size_t)c * HW + pix]);
}

// ---------------------------------------------------------------------------
// Fallback: used only if ws_size can't hold the repacked texture.
// ---------------------------------------------------------------------------
__global__ __launch_bounds__(256)
void resample_fallback_kernel(const float* __restrict__ x,
                              const int*   __restrict__ quad,
                              const float2* __restrict__ uv2,
                              float* __restrict__ out)
{
    const int gid = blockIdx.x * 256 + threadIdx.x;
    const int pix = gid & (HW - 1);
    const int bc  = gid >> HW_SHIFT;

    const float2 t = uv2[pix];
    const int    f = quad[pix];

    const float u = t.x;
    const float v = t.y;

    int u0 = (int)floorf(u);
    int v0 = (int)floorf(v);
    u0 = min(max(u0, 0), ND - 2);
    v0 = min(max(v0, 0), ND - 2);

    const float du = u - (float)u0;
    const float dv = v - (float)v0;

    const float w00 = (1.0f - du) * (1.0f - dv);
    const float w01 = du * (1.0f - dv);
    const float w10 = (1.0f - du) * dv;
    const float w11 = du * dv;

    const float* p = x + ((size_t)bc * FD + (size_t)f) * NN + v0 * ND + u0;
    out[gid] = p[0] * w00 + p[1] * w01 + p[ND] * w10 + p[ND + 1] * w11;
}

extern "C" void kernel_launch(void* const* d_in, const int* in_sizes, int n_in,
                              void* d_out, int out_size, void* d_ws, size_t ws_size,
                              hipStream_t stream)
{
    const float*  x    = (const float*)d_in[0];
    const int*    quad = (const int*)d_in[1];
    const float2* uv2  = (const float2*)d_in[2];
    float*        out  = (float*)d_out;

    if (ws_size >= YH_BYTES) {
        __half* y = (__half*)d_ws;
        repack_kernel<<<FD * ND, 256, 0, stream>>>(x, y);      // 10240 blocks
        gather_kernel<<<HW / 256, 256, 0, stream>>>(y, quad, uv2, out);  // 2048 blocks
    } else {
        const int total = BC * HW;
        resample_fallback_kernel<<<total / 256, 256, 0, stream>>>(x, quad, uv2, out);
    }
}